// Round 10
// baseline (1245.947 us; speedup 1.0000x reference)
//
#include <hip/hip_runtime.h>
#include <cmath>

// RouterCond fused, round 10: 2 blocks/CU (two independent barrier domains ->
// phase overlap). BM=64, 4 waves/block (32x128 tiles). A fragments loaded
// per-lane straight from global x + in-register fp16x2 split (no A LDS).
// B-only LDS dbuf (64 KB) via global_load_lds; H/Lred alias dead halves.
#define N_TOK 32768
#define D0    1024
#define DCC   512
#define DIN   1536
#define JD    3072
#define NE    64
#define BM    64
#define BJ    256
#define BK    32
#define NJC   (JD/BJ)      // 12
#define NIT   (DIN/BK)     // 48
#define NTH   256
#define EPSV  1e-9f

typedef _Float16 half8 __attribute__((ext_vector_type(8)));
typedef float    f32x4 __attribute__((ext_vector_type(4)));

// ---- LDS: B double buffer only. Buf = [pl(2)][koct(4)][col(256)] granules(16B) = 32 KB.
#define SZ_B  32768
#define LDS_TOTAL 65536
// GEMM2 H slabs: 4 waves x 4608 B inside buf1 region (dead during GEMM2).
#define OFF_H 32768
// epilogue: Lred [64][68] f32 = 17408 + scalars, inside buf0 region (dead).
#define OFF_LRED 0
#define OFF_EPI  18432

// ---- workspace: pre-split + pre-transposed fp16 planes (granule = 8 halves)
#define W1T_G (192*3072)
#define W2T_G (384*64)

__device__ __forceinline__ f32x4 mfma16(half8 a, half8 b, f32x4 c) {
    return __builtin_amdgcn_mfma_f32_16x16x32_f16(a, b, c, 0, 0, 0);
}

__device__ __forceinline__ void split8(const float4 v0, const float4 v1, half8& hh, half8& hl) {
    float f[8] = {v0.x, v0.y, v0.z, v0.w, v1.x, v1.y, v1.z, v1.w};
    #pragma unroll
    for (int i = 0; i < 8; ++i) {
        _Float16 h = (_Float16)f[i];
        hh[i] = h;
        hl[i] = (_Float16)(f[i] - (float)h);
    }
}

__device__ __forceinline__ void gload16(const void* g, void* l) {
    __builtin_amdgcn_global_load_lds(
        (const __attribute__((address_space(1))) unsigned int*)g,
        (__attribute__((address_space(3))) unsigned int*)l, 16, 0, 0);
}

// -------- prologue kernels (r7-r9 proven) --------
__global__ void presplit_w1t(const float* __restrict__ W1,
                             _Float16* __restrict__ hi, _Float16* __restrict__ lo) {
    int g = blockIdx.x * blockDim.x + threadIdx.x;
    if (g >= W1T_G) return;
    const int j  = g % JD;
    const int ko = g / JD;
    const float* src = W1 + (size_t)j * DIN + ko * 8;
    float4 v0 = *(const float4*)src;
    float4 v1 = *(const float4*)(src + 4);
    half8 h, l;
    split8(v0, v1, h, l);
    *(half8*)(hi + (size_t)g * 8) = h;
    *(half8*)(lo + (size_t)g * 8) = l;
}

__global__ void presplit_w2t(const float* __restrict__ W2,
                             _Float16* __restrict__ hi, _Float16* __restrict__ lo) {
    int g = blockIdx.x * blockDim.x + threadIdx.x;
    if (g >= W2T_G) return;
    const int e  = g & 63;
    const int jo = g >> 6;
    const float* src = W2 + (size_t)e * JD + jo * 8;
    float4 v0 = *(const float4*)src;
    float4 v1 = *(const float4*)(src + 4);
    half8 h, l;
    split8(v0, v1, h, l);
    *(half8*)(hi + (size_t)g * 8) = h;
    *(half8*)(lo + (size_t)g * 8) = l;
}

// -------- main fused kernel --------
__global__ __launch_bounds__(NTH, 2)
void router_v10(const float* __restrict__ inp, const float* __restrict__ cnd,
                const _Float16* __restrict__ W1h, const _Float16* __restrict__ W1l,
                const _Float16* __restrict__ W2h, const _Float16* __restrict__ W2l,
                float* __restrict__ out_mask, float* __restrict__ out_topi,
                float* __restrict__ out_rp, float* __restrict__ out_probs)
{
    __shared__ __align__(16) char smem[LDS_TOTAL];

    const int tid  = threadIdx.x;     // 0..255
    const int lane = tid & 63;
    const int w    = tid >> 6;        // wave 0..3
    const int tg   = w >> 1;          // token half: rows tg*32..+31
    const int jg   = w & 1;           // j half: cols jg*128..+127
    const int l15  = lane & 15;
    const int lg   = lane >> 4;       // k-oct 0..3
    const int t0   = blockIdx.x * BM;

    // B staging roles: wave -> (plane, koct pair)
    const int spl = w >> 1;           // 0,0,1,1
    const int sko = (w & 1) * 2;      // 0,2

    // B frag byte offsets within a buffer (hi plane; lo at +16384)
    int boff[8];
    #pragma unroll
    for (int jf = 0; jf < 8; ++jf)
        boff[jf] = (lg * 256 + jg * 128 + jf * 16 + l15) * 16;

    // A per-lane row pointers (fragment rows: lane&15 within each 16-row tile)
    const float* pA[2];
    const float* pC[2];
    #pragma unroll
    for (int tf = 0; tf < 2; ++tf) {
        const int row = t0 + tg * 32 + tf * 16 + l15;
        pA[tf] = inp + (size_t)row * D0;
        pC[tf] = cnd + (size_t)row * DCC;
    }

    // wave-private H slab in buf1 region: [32][36] halves, hi then lo
    _Float16* const myHh = (_Float16*)(smem + OFF_H + w * 4608);
    _Float16* const myHl = myHh + 1152;

    const f32x4 vzero = {0.f, 0.f, 0.f, 0.f};
    f32x4 lacc[4] = {vzero, vzero, vzero, vzero};   // 64 tok x 16 experts (e0 = w*16)

    // prologue: stage B(jc=0,it=0) -> buf0; prefetch A(it=0)
    float4 xv[2][2];
    {
        #pragma unroll
        for (int d = 0; d < 2; ++d) {
            const int ko = sko + d;
            #pragma unroll
            for (int q = 0; q < 4; ++q) {
                const _Float16* src = (spl ? W1l : W1h) +
                    ((size_t)ko * JD + q * 64 + lane) * 8;
                gload16(src, smem + ((spl * 4 + ko) * 256 + q * 64) * 16);
            }
        }
        #pragma unroll
        for (int tf = 0; tf < 2; ++tf) {
            const float* s = pA[tf] + lg * 8;
            xv[tf][0] = *(const float4*)s;
            xv[tf][1] = *(const float4*)(s + 4);
        }
    }
    __syncthreads();

    for (int jc = 0; jc < NJC; ++jc) {
        f32x4 acc1[2][8];
        #pragma unroll
        for (int tf = 0; tf < 2; ++tf)
            #pragma unroll
            for (int jf = 0; jf < 8; ++jf) acc1[tf][jf] = vzero;

        for (int it = 0; it < NIT; ++it) {
            const int cur = it & 1;
            const bool more = !(jc == NJC - 1 && it == NIT - 1);
            // split current A fragments (registers only)
            half8 ah[2], al[2];
            #pragma unroll
            for (int tf = 0; tf < 2; ++tf)
                split8(xv[tf][0], xv[tf][1], ah[tf], al[tf]);
            if (more) {
                const int itn = (it == NIT - 1) ? 0 : it + 1;
                const int jcn = (it == NIT - 1) ? jc + 1 : jc;
                // issue next B gloads into other buffer (full-iter latency window)
                char* bb = smem + (cur ^ 1) * SZ_B;
                #pragma unroll
                for (int d = 0; d < 2; ++d) {
                    const int ko = sko + d;
                    const size_t kog = (size_t)(itn * 4 + ko) * JD + jcn * BJ;
                    #pragma unroll
                    for (int q = 0; q < 4; ++q) {
                        const _Float16* src = (spl ? W1l : W1h) + (kog + q * 64 + lane) * 8;
                        gload16(src, bb + ((spl * 4 + ko) * 256 + q * 64) * 16);
                    }
                }
                // prefetch next A into registers
                const int k0 = itn * BK + lg * 8;
                #pragma unroll
                for (int tf = 0; tf < 2; ++tf) {
                    const float* s = (itn < 32) ? (pA[tf] + k0) : (pC[tf] + k0 - D0);
                    xv[tf][0] = *(const float4*)s;
                    xv[tf][1] = *(const float4*)(s + 4);
                }
            }
            // B frags from LDS (contiguous granules, conflict-free) + MFMAs
            const char* bb = smem + cur * SZ_B;
            #pragma unroll
            for (int jf = 0; jf < 8; ++jf) {
                half8 bh = *(const half8*)(bb + boff[jf]);
                half8 bl = *(const half8*)(bb + 16384 + boff[jf]);
                #pragma unroll
                for (int tf = 0; tf < 2; ++tf) {
                    acc1[tf][jf] = mfma16(ah[tf], bh, acc1[tf][jf]);
                    acc1[tf][jf] = mfma16(ah[tf], bl, acc1[tf][jf]);
                    acc1[tf][jf] = mfma16(al[tf], bh, acc1[tf][jf]);
                }
            }
            __syncthreads();   // one barrier per iter (drains gloads + fences bufs)
        }

        // ---- GEMM2: 4 rounds; each wave writes its 2 jf-chunks (32 j) into its
        //      slab, then computes 64 tok x 16 experts over this round's 64 j.
        #pragma unroll
        for (int r = 0; r < 4; ++r) {
            #pragma unroll
            for (int c = 0; c < 2; ++c) {
                const int jf = 2 * r + c;
                #pragma unroll
                for (int tf = 0; tf < 2; ++tf)
                    #pragma unroll
                    for (int rr = 0; rr < 4; ++rr) {
                        const float v = acc1[tf][jf][rr];
                        const float gv = 0.5f * v * (1.0f + erff(v * 0.70710678118654752f));
                        const _Float16 gh = (_Float16)gv;
                        const _Float16 gl = (_Float16)(gv - (float)gh);
                        const int o = (tf * 16 + lg * 4 + rr) * 36 + c * 16 + l15;
                        myHh[o] = gh; myHl[o] = gl;
                    }
            }
            __syncthreads();
            #pragma unroll
            for (int jg2 = 0; jg2 < 2; ++jg2) {
                const int jo = jc * 32 + jg2 * 16 + r * 4 + lg;
                const size_t wg = ((size_t)jo * 64 + w * 16 + l15) * 8;
                half8 b2h = *(const half8*)(W2h + wg);
                half8 b2l = *(const half8*)(W2l + wg);
                #pragma unroll
                for (int tf2 = 0; tf2 < 4; ++tf2) {
                    const _Float16* sh = (const _Float16*)(smem + OFF_H + ((tf2 >> 1) * 2 + jg2) * 4608);
                    const _Float16* sl = sh + 1152;
                    const int o = ((tf2 & 1) * 16 + l15) * 36 + lg * 8;
                    half8 a2h = *(const half8*)(sh + o);
                    half8 a2l = *(const half8*)(sl + o);
                    lacc[tf2] = mfma16(a2h, b2h, lacc[tf2]);
                    lacc[tf2] = mfma16(a2h, b2l, lacc[tf2]);
                    lacc[tf2] = mfma16(a2l, b2h, lacc[tf2]);
                }
            }
            __syncthreads();
        }
    }

    // ---- epilogue: wave owns 64 tok x 16 exp -> Lred, softmax + top-2, write
    float* const Lred = (float*)(smem + OFF_LRED);
    #pragma unroll
    for (int tf2 = 0; tf2 < 4; ++tf2)
        #pragma unroll
        for (int rr = 0; rr < 4; ++rr)
            Lred[(tf2 * 16 + lg * 4 + rr) * 68 + w * 16 + l15] = lacc[tf2][rr];
    __syncthreads();

    float* const mA   = (float*)(smem + OFF_EPI);
    float* const invA = mA + BM;
    int*   const i1A  = (int*)(invA + BM);
    int*   const i2A  = i1A + BM;
    float* const rp1A = (float*)(i2A + BM);
    float* const rp2A = rp1A + BM;

    if (tid < BM) {
        const float* row = Lred + tid * 68;
        float m = -3.402823466e38f;
        for (int e = 0; e < NE; ++e) m = fmaxf(m, row[e]);
        float s = 0.f, v1 = -3.402823466e38f, v2 = -3.402823466e38f;
        int i1 = 0, i2 = 0;
        for (int e = 0; e < NE; ++e) {
            const float v = row[e];
            s += expf(v - m);
            if (v > v1)      { v2 = v1; i2 = i1; v1 = v; i1 = e; }
            else if (v > v2) { v2 = v; i2 = e; }
        }
        const float inv = 1.f / s;
        const float p1 = fminf(expf(v1 - m) * inv + EPSV, 1.f - EPSV);
        const float p2 = fminf(expf(v2 - m) * inv + EPSV, 1.f - EPSV);
        mA[tid] = m; invA[tid] = inv; i1A[tid] = i1; i2A[tid] = i2;
        const float den = p1 + p2;
        rp1A[tid] = p1 / den; rp2A[tid] = p2 / den;
    }
    __syncthreads();

    for (int idx = tid; idx < BM * NE; idx += NTH) {
        const int r = idx >> 6, e = idx & 63;
        const size_t o = (size_t)(t0 + r) * NE + e;
        const float p = fminf(expf(Lred[r * 68 + e] - mA[r]) * invA[r] + EPSV, 1.f - EPSV);
        const int b1 = (e == i1A[r]), b2 = (e == i2A[r]);
        out_probs[o] = p;
        out_mask[o]  = (b1 | b2) ? 1.f : 0.f;
        out_rp[o]    = b1 ? rp1A[r] : (b2 ? rp2A[r] : 0.f);
    }
    if (tid < BM * 2) {
        const int r = tid >> 1, q = tid & 1;
        out_topi[(size_t)(t0 + r) * 2 + q] = (float)(q ? i2A[r] : i1A[r]);
    }
}

extern "C" void kernel_launch(void* const* d_in, const int* in_sizes, int n_in,
                              void* d_out, int out_size, void* d_ws, size_t ws_size,
                              hipStream_t stream) {
    const float* inp = (const float*)d_in[0];
    const float* cnd = (const float*)d_in[1];
    const float* W1  = (const float*)d_in[2];
    const float* W2  = (const float*)d_in[3];

    float* out = (float*)d_out;
    const size_t NT = (size_t)N_TOK;
    float* out_mask  = out;
    float* out_topi  = out + NT * NE;
    float* out_rp    = out + NT * NE + NT * 2;
    float* out_probs = out + NT * NE + NT * 2 + NT * NE;

    _Float16* W1h = (_Float16*)d_ws;
    _Float16* W1l = W1h + (size_t)W1T_G * 8;
    _Float16* W2h = W1l + (size_t)W1T_G * 8;
    _Float16* W2l = W2h + (size_t)W2T_G * 8;

    hipLaunchKernelGGL(presplit_w1t, dim3((W1T_G + 255) / 256), dim3(256), 0, stream, W1, W1h, W1l);
    hipLaunchKernelGGL(presplit_w2t, dim3((W2T_G + 255) / 256), dim3(256), 0, stream, W2, W2h, W2l);
    hipLaunchKernelGGL(router_v10, dim3(N_TOK / BM), dim3(NTH), 0, stream,
                       inp, cnd, W1h, W1l, W2h, W2l,
                       out_mask, out_topi, out_rp, out_probs);
}

// Round 11
// 1227.558 us; speedup vs baseline: 1.0150x; 1.0150x over previous
//
#include <hip/hip_runtime.h>
#include <cmath>

// RouterCond fused, round 11: r9 geometry + counted-vmcnt software pipeline.
// B tri-buffered via global_load_lds issued 2 iters ahead; barriers are
// lgkmcnt(0)+raw s_barrier (NO vmcnt drain); A-loads issued first so the
// compiler's counted xv-wait retires exactly the 1-iter-old B batch.
#define N_TOK 32768
#define D0    1024
#define DCC   512
#define DIN   1536
#define JD    3072
#define NE    64
#define BM    128
#define BJ    256
#define BK    32
#define NJC   (JD/BJ)      // 12
#define NIT   (DIN/BK)     // 48
#define NTH   512
#define HS    36
#define EPSV  1e-9f

typedef _Float16 half8 __attribute__((ext_vector_type(8)));
typedef float    f32x4 __attribute__((ext_vector_type(4)));

// ---- LDS: 16B granules. A buf = [pl(2)][koct(4)][row(128)] = 16KB, 2 bufs.
//      B buf = [pl(2)][koct(4)][col(256)] = 32KB, 3 bufs (2-deep prefetch).
#define SZ_A  16384
#define SZ_B  32768
#define OFF_A 0                    // A bufs: 0, 16384
#define OFF_B 32768                // B bufs: 32768, 65536, 98304
#define LDS_TOTAL 131072
// GEMM2 H slabs (8 x 9216 = 73728) alias B region (dead between jc's).
#define OFF_H    32768
// epilogue: Lred [128][68] f32 = 34816 at 0 (A + B0-head, dead); scalars after.
#define OFF_LRED 0
#define OFF_EPI  36864

// ---- workspace: pre-split + pre-transposed fp16 planes (granule = 8 halves)
#define W1T_G (192*3072)
#define W2T_G (384*64)

__device__ __forceinline__ f32x4 mfma16(half8 a, half8 b, f32x4 c) {
    return __builtin_amdgcn_mfma_f32_16x16x32_f16(a, b, c, 0, 0, 0);
}

__device__ __forceinline__ void split8(const float4 v0, const float4 v1, half8& hh, half8& hl) {
    float f[8] = {v0.x, v0.y, v0.z, v0.w, v1.x, v1.y, v1.z, v1.w};
    #pragma unroll
    for (int i = 0; i < 8; ++i) {
        _Float16 h = (_Float16)f[i];
        hh[i] = h;
        hl[i] = (_Float16)(f[i] - (float)h);
    }
}

__device__ __forceinline__ void gload16(const void* g, void* l) {
    __builtin_amdgcn_global_load_lds(
        (const __attribute__((address_space(1))) unsigned int*)g,
        (__attribute__((address_space(3))) unsigned int*)l, 16, 0, 0);
}

// barrier WITHOUT vmcnt drain: outstanding global_load_lds fly across.
#define SOFT_BARRIER() do { \
    asm volatile("s_waitcnt lgkmcnt(0)" ::: "memory"); \
    __builtin_amdgcn_s_barrier(); \
} while (0)

// -------- prologue kernels (r7-r9 proven) --------
__global__ void presplit_w1t(const float* __restrict__ W1,
                             _Float16* __restrict__ hi, _Float16* __restrict__ lo) {
    int g = blockIdx.x * blockDim.x + threadIdx.x;
    if (g >= W1T_G) return;
    const int j  = g % JD;
    const int ko = g / JD;
    const float* src = W1 + (size_t)j * DIN + ko * 8;
    float4 v0 = *(const float4*)src;
    float4 v1 = *(const float4*)(src + 4);
    half8 h, l;
    split8(v0, v1, h, l);
    *(half8*)(hi + (size_t)g * 8) = h;
    *(half8*)(lo + (size_t)g * 8) = l;
}

__global__ void presplit_w2t(const float* __restrict__ W2,
                             _Float16* __restrict__ hi, _Float16* __restrict__ lo) {
    int g = blockIdx.x * blockDim.x + threadIdx.x;
    if (g >= W2T_G) return;
    const int e  = g & 63;
    const int jo = g >> 6;
    const float* src = W2 + (size_t)e * JD + jo * 8;
    float4 v0 = *(const float4*)src;
    float4 v1 = *(const float4*)(src + 4);
    half8 h, l;
    split8(v0, v1, h, l);
    *(half8*)(hi + (size_t)g * 8) = h;
    *(half8*)(lo + (size_t)g * 8) = l;
}

// -------- main fused kernel --------
__global__ __launch_bounds__(NTH, 1)
void router_v11(const float* __restrict__ inp, const float* __restrict__ cnd,
                const _Float16* __restrict__ W1h, const _Float16* __restrict__ W1l,
                const _Float16* __restrict__ W2h, const _Float16* __restrict__ W2l,
                float* __restrict__ out_mask, float* __restrict__ out_topi,
                float* __restrict__ out_rp, float* __restrict__ out_probs)
{
    __shared__ __align__(16) char smem[LDS_TOTAL];

    const int tid  = threadIdx.x;
    const int lane = tid & 63;
    const int w    = tid >> 6;      // wave 0..7
    const int tg   = w >> 2;        // token half: rows tg*64..+63
    const int jg   = w & 3;         // j quarter (64 cols) / expert group (16)
    const int l15  = lane & 15;
    const int lg   = lane >> 4;     // 0..3 = k-oct
    const int t0   = blockIdx.x * BM;

    // A staging: wave -> k-oct (w>>1), lanes -> consecutive rows (conflict-free)
    const int akoct = w >> 1;                 // 0..3
    const int arow  = (w & 1) * 64 + lane;    // 0..127
    // B staging: wave -> (plane, koct); 4 gload16 of 64 cols each
    const int bplane = w >> 2;                // 0..1
    const int bkoct  = w & 3;                 // 0..3

    // frag byte offsets within a buffer (hi plane; lo at +8192 A / +16384 B)
    int aoff[4], boff[4];
    #pragma unroll
    for (int tf = 0; tf < 4; ++tf) aoff[tf] = (lg*128 + tg*64 + tf*16 + l15) * 16;
    #pragma unroll
    for (int jf = 0; jf < 4; ++jf) boff[jf] = (lg*256 + jg*64 + jf*16 + l15) * 16;

    const f32x4 vzero = {0.f, 0.f, 0.f, 0.f};
    f32x4 lacc[4] = {vzero, vzero, vzero, vzero};   // 64 tokens x 16 experts

    const float* const xrowA = inp + (size_t)(t0 + arow) * D0;
    const float* const xrowC = cnd + (size_t)(t0 + arow) * DCC;
    const _Float16* const Wbp = bplane ? W1l : W1h;

    // wave-private H slab: [64 tok][HS] halves, hi then lo (2304 halves each)
    _Float16* const myHh = (_Float16*)(smem + OFF_H + w * 9216);
    _Float16* const myHl = myHh + 2304;

    for (int jc = 0; jc < NJC; ++jc) {
        f32x4 acc1[4][4];
        #pragma unroll
        for (int tf = 0; tf < 4; ++tf)
            #pragma unroll
            for (int jf = 0; jf < 4; ++jf) acc1[tf][jf] = vzero;

        // ---- prologue: A(it0)->Abuf0; B(it0)->Bbuf0, B(it1)->Bbuf1
        {
            float4 v0 = *(const float4*)(xrowA + akoct * 8);   // it0 is inp side
            float4 v1 = *(const float4*)(xrowA + akoct * 8 + 4);
            #pragma unroll
            for (int d = 0; d < 2; ++d) {
                const int ko = d * 4 + bkoct;
                const _Float16* src = Wbp + ((size_t)ko * JD + jc * BJ) * 8;
                char* dst = smem + OFF_B + d * SZ_B + (bplane * 4 + bkoct) * 4096;
                #pragma unroll
                for (int q = 0; q < 4; ++q)
                    gload16(src + (size_t)(q * 64 + lane) * 8, dst + q * 1024);
            }
            half8 hh, hl;
            split8(v0, v1, hh, hl);
            const int g = (akoct * 128 + arow) * 16;
            *(half8*)(smem + OFF_A + g) = hh;
            *(half8*)(smem + OFF_A + 8192 + g) = hl;
            // full drain once per jc (both B batches + A writes)
            asm volatile("s_waitcnt vmcnt(0) lgkmcnt(0)" ::: "memory");
            __builtin_amdgcn_s_barrier();
        }

        for (int it = 0; it < NIT; ++it) {
            const bool haveA = (it + 1 < NIT);
            const bool haveB = (it + 2 < NIT);
            float4 xv0, xv1;
            if (haveA) {   // A loads FIRST (in-order vmcnt: xv-wait retires old B batch)
                const int k = (it + 1) * BK + akoct * 8;
                const float* sx = (k < D0) ? (xrowA + k) : (xrowC + k - D0);
                xv0 = *(const float4*)sx;
                xv1 = *(const float4*)(sx + 4);
                __builtin_amdgcn_sched_barrier(0);   // pin A-before-B issue order
            }
            if (haveB) {   // B gloads for iter it+2 -> buf[(it+2)%3]
                const int ko = (it + 2) * 4 + bkoct;
                const _Float16* src = Wbp + ((size_t)ko * JD + jc * BJ) * 8;
                char* dst = smem + OFF_B + ((it + 2) % 3) * SZ_B
                          + (bplane * 4 + bkoct) * 4096;
                #pragma unroll
                for (int q = 0; q < 4; ++q)
                    gload16(src + (size_t)(q * 64 + lane) * 8, dst + q * 1024);
            }
            // fragment reads from current buffers (contiguous, conflict-free)
            const char* ab = smem + OFF_A + (it & 1) * SZ_A;
            const char* bb = smem + OFF_B + (it % 3) * SZ_B;
            half8 ah[4], al[4], bh[4], bl[4];
            #pragma unroll
            for (int tf = 0; tf < 4; ++tf) {
                ah[tf] = *(const half8*)(ab + aoff[tf]);
                al[tf] = *(const half8*)(ab + 8192 + aoff[tf]);
            }
            #pragma unroll
            for (int jf = 0; jf < 4; ++jf) {
                bh[jf] = *(const half8*)(bb + boff[jf]);
                bl[jf] = *(const half8*)(bb + 16384 + boff[jf]);
            }
            #pragma unroll
            for (int tf = 0; tf < 4; ++tf)
                #pragma unroll
                for (int jf = 0; jf < 4; ++jf) {
                    acc1[tf][jf] = mfma16(ah[tf], bh[jf], acc1[tf][jf]);
                    acc1[tf][jf] = mfma16(ah[tf], bl[jf], acc1[tf][jf]);
                    acc1[tf][jf] = mfma16(al[tf], bh[jf], acc1[tf][jf]);
                }
            if (haveA) {   // compiler emits counted vmcnt for xv (retires old B)
                half8 hh, hl;
                split8(xv0, xv1, hh, hl);
                char* nab = smem + OFF_A + ((it + 1) & 1) * SZ_A;
                const int g = (akoct * 128 + arow) * 16;
                *(half8*)(nab + g) = hh;
                *(half8*)(nab + 8192 + g) = hl;
            }
            if (it < NIT - 1) {
                SOFT_BARRIER();        // lgkmcnt(0) only; fresh B gloads fly across
            } else {
                __syncthreads();       // jc-boundary full drain (12 total)
            }
        }

        // ---- expert-split GEMM2 (r9-proven): 2 rounds of 32-j chunks.
        #pragma unroll
        for (int r = 0; r < 2; ++r) {
            #pragma unroll
            for (int c = 0; c < 2; ++c) {
                const int jf = 2*r + c;
                #pragma unroll
                for (int tf = 0; tf < 4; ++tf)
                    #pragma unroll
                    for (int rr = 0; rr < 4; ++rr) {
                        const float v = acc1[tf][jf][rr];
                        const float gv = 0.5f * v * (1.0f + erff(v * 0.70710678118654752f));
                        const _Float16 gh = (_Float16)gv;
                        const _Float16 gl = (_Float16)(gv - (float)gh);
                        const int o = (tf*16 + lg*4 + rr) * HS + c*16 + l15;
                        myHh[o] = gh; myHl[o] = gl;
                    }
            }
            __syncthreads();
            #pragma unroll
            for (int s = 0; s < 4; ++s) {
                const _Float16* sh = (const _Float16*)(smem + OFF_H + (tg*4 + s) * 9216);
                const _Float16* sl = sh + 2304;
                const int jo = jc*32 + s*8 + r*4 + lg;
                const size_t wg = ((size_t)jo * 64 + jg*16 + l15) * 8;
                half8 b2h = *(const half8*)(W2h + wg);
                half8 b2l = *(const half8*)(W2l + wg);
                #pragma unroll
                for (int tf = 0; tf < 4; ++tf) {
                    const int o = (tf*16 + l15) * HS + lg*8;
                    half8 a2h = *(const half8*)(sh + o);
                    half8 a2l = *(const half8*)(sl + o);
                    lacc[tf] = mfma16(a2h, b2h, lacc[tf]);
                    lacc[tf] = mfma16(a2h, b2l, lacc[tf]);
                    lacc[tf] = mfma16(a2l, b2h, lacc[tf]);
                }
            }
            __syncthreads();
        }
    }

    // ---- epilogue: wave owns 64tok x 16exp -> Lred once, softmax + top-2, out
    float* const Lred = (float*)(smem + OFF_LRED);
    #pragma unroll
    for (int tf = 0; tf < 4; ++tf)
        #pragma unroll
        for (int rr = 0; rr < 4; ++rr)
            Lred[(tg*64 + tf*16 + lg*4 + rr) * 68 + jg*16 + l15] = lacc[tf][rr];
    __syncthreads();

    float* const mA   = (float*)(smem + OFF_EPI);
    float* const invA = mA + BM;
    int*   const i1A  = (int*)(invA + BM);
    int*   const i2A  = i1A + BM;
    float* const rp1A = (float*)(i2A + BM);
    float* const rp2A = rp1A + BM;

    if (tid < BM) {
        const float* row = Lred + tid * 68;
        float m = -3.402823466e38f;
        for (int e = 0; e < NE; ++e) m = fmaxf(m, row[e]);
        float s = 0.f, v1 = -3.402823466e38f, v2 = -3.402823466e38f;
        int i1 = 0, i2 = 0;
        for (int e = 0; e < NE; ++e) {
            const float v = row[e];
            s += expf(v - m);
            if (v > v1)      { v2 = v1; i2 = i1; v1 = v; i1 = e; }
            else if (v > v2) { v2 = v; i2 = e; }
        }
        const float inv = 1.f / s;
        const float p1 = fminf(expf(v1 - m) * inv + EPSV, 1.f - EPSV);
        const float p2 = fminf(expf(v2 - m) * inv + EPSV, 1.f - EPSV);
        mA[tid] = m; invA[tid] = inv; i1A[tid] = i1; i2A[tid] = i2;
        const float den = p1 + p2;
        rp1A[tid] = p1 / den; rp2A[tid] = p2 / den;
    }
    __syncthreads();

    for (int idx = tid; idx < BM * NE; idx += NTH) {
        const int r = idx >> 6, e = idx & 63;
        const size_t o = (size_t)(t0 + r) * NE + e;
        const float p = fminf(expf(Lred[r * 68 + e] - mA[r]) * invA[r] + EPSV, 1.f - EPSV);
        const int b1 = (e == i1A[r]), b2 = (e == i2A[r]);
        out_probs[o] = p;
        out_mask[o]  = (b1 | b2) ? 1.f : 0.f;
        out_rp[o]    = b1 ? rp1A[r] : (b2 ? rp2A[r] : 0.f);
    }
    if (tid < BM * 2) {
        const int r = tid >> 1, q = tid & 1;
        out_topi[(size_t)(t0 + r) * 2 + q] = (float)(q ? i2A[r] : i1A[r]);
    }
}

extern "C" void kernel_launch(void* const* d_in, const int* in_sizes, int n_in,
                              void* d_out, int out_size, void* d_ws, size_t ws_size,
                              hipStream_t stream) {
    const float* inp = (const float*)d_in[0];
    const float* cnd = (const float*)d_in[1];
    const float* W1  = (const float*)d_in[2];
    const float* W2  = (const float*)d_in[3];

    float* out = (float*)d_out;
    const size_t NT = (size_t)N_TOK;
    float* out_mask  = out;
    float* out_topi  = out + NT * NE;
    float* out_rp    = out + NT * NE + NT * 2;
    float* out_probs = out + NT * NE + NT * 2 + NT * NE;

    _Float16* W1h = (_Float16*)d_ws;
    _Float16* W1l = W1h + (size_t)W1T_G * 8;
    _Float16* W2h = W1l + (size_t)W1T_G * 8;
    _Float16* W2l = W2h + (size_t)W2T_G * 8;

    hipLaunchKernelGGL(presplit_w1t, dim3((W1T_G + 255) / 256), dim3(256), 0, stream, W1, W1h, W1l);
    hipLaunchKernelGGL(presplit_w2t, dim3((W2T_G + 255) / 256), dim3(256), 0, stream, W2, W2h, W2l);
    hipLaunchKernelGGL(router_v11, dim3(N_TOK / BM), dim3(NTH), 0, stream,
                       inp, cnd, W1h, W1l, W2h, W2l,
                       out_mask, out_topi, out_rp, out_probs);
}